// Round 1
// baseline (1023.939 us; speedup 1.0000x reference)
//
#include <hip/hip_runtime.h>
#include <math.h>

constexpr int IN_C = 1024;
constexpr int HID = 64;
constexpr int HEADS = 4;
constexpr int F1 = HEADS * HID;  // 256
constexpr int OUT_C = 64;
constexpr float NEG = 0.2f;

__device__ __forceinline__ float leaky(float x) { return x > 0.f ? x : NEG * x; }

// ---------------- GEMM: C[M,N] = A[M,K] * B[N,K]^T (both row-major along K) ---------
__global__ __launch_bounds__(256) void gemm_nt(const float* __restrict__ A,
                                               const float* __restrict__ B,
                                               float* __restrict__ C,
                                               int M, int N, int K) {
  __shared__ float As[32][68];
  __shared__ float Bs[32][68];
  const int bm = blockIdx.x * 64;
  const int bn = blockIdx.y * 64;
  const int tid = threadIdx.x;
  const int tx = tid & 15;
  const int ty = tid >> 4;
  float acc[4][4] = {{0.f, 0.f, 0.f, 0.f}};
  const int lr = tid >> 3;        // 0..31: row within 32-row group
  const int lc = (tid & 7) << 2;  // k-offset 0..28 step 4
  for (int kt = 0; kt < K; kt += 32) {
#pragma unroll
    for (int p = 0; p < 2; ++p) {
      int r = lr + p * 32;
      int gr = bm + r;
      float4 va = make_float4(0.f, 0.f, 0.f, 0.f);
      if (gr < M) va = *(const float4*)(A + (size_t)gr * K + kt + lc);
      As[lc + 0][r] = va.x; As[lc + 1][r] = va.y;
      As[lc + 2][r] = va.z; As[lc + 3][r] = va.w;
      int gn = bn + r;
      float4 vb = make_float4(0.f, 0.f, 0.f, 0.f);
      if (gn < N) vb = *(const float4*)(B + (size_t)gn * K + kt + lc);
      Bs[lc + 0][r] = vb.x; Bs[lc + 1][r] = vb.y;
      Bs[lc + 2][r] = vb.z; Bs[lc + 3][r] = vb.w;
    }
    __syncthreads();
#pragma unroll
    for (int k = 0; k < 32; ++k) {
      float4 a = *(const float4*)&As[k][ty * 4];
      float4 b = *(const float4*)&Bs[k][tx * 4];
      float av[4] = {a.x, a.y, a.z, a.w};
      float bv[4] = {b.x, b.y, b.z, b.w};
#pragma unroll
      for (int i = 0; i < 4; ++i)
#pragma unroll
        for (int j = 0; j < 4; ++j) acc[i][j] = fmaf(av[i], bv[j], acc[i][j]);
    }
    __syncthreads();
  }
#pragma unroll
  for (int i = 0; i < 4; ++i) {
    int row = bm + ty * 4 + i;
    if (row < M) {
#pragma unroll
      for (int j = 0; j < 4; ++j)
        C[(size_t)row * N + bn + tx * 4 + j] = acc[i][j];
    }
  }
}

// ---------------- CSR build ----------------
__global__ void degree_kernel(const int* __restrict__ ei, int E, int N,
                              int* __restrict__ deg) {
  int e = blockIdx.x * blockDim.x + threadIdx.x;
  if (e >= E + N) return;
  int dst = (e < E) ? ei[E + e] : (e - E);  // self-loops appended
  atomicAdd(&deg[dst], 1);
}

__global__ __launch_bounds__(1024) void scan_kernel(const int* __restrict__ deg,
                                                    int* __restrict__ row_ptr, int n) {
  __shared__ int sm[1024];
  __shared__ int carry_s;
  const int tid = threadIdx.x;
  if (tid == 0) carry_s = 0;
  __syncthreads();
  for (int base = 0; base < n; base += 1024) {
    int i = base + tid;
    int v = (i < n) ? deg[i] : 0;
    sm[tid] = v;
    __syncthreads();
    for (int off = 1; off < 1024; off <<= 1) {
      int t = (tid >= off) ? sm[tid - off] : 0;
      __syncthreads();
      sm[tid] += t;
      __syncthreads();
    }
    int inc = sm[tid];
    int carry = carry_s;
    if (i < n) row_ptr[i + 1] = carry + inc;
    if (tid == 0 && base == 0) row_ptr[0] = 0;
    __syncthreads();
    if (tid == 1023) carry_s = carry + inc;
    __syncthreads();
  }
}

__global__ void scatter_kernel(const int* __restrict__ ei, int E, int N,
                               const int* __restrict__ row_ptr, int* __restrict__ fill,
                               int* __restrict__ col) {
  int e = blockIdx.x * blockDim.x + threadIdx.x;
  if (e >= E + N) return;
  int src, dst;
  if (e < E) { src = ei[e]; dst = ei[E + e]; }
  else       { src = e - E; dst = e - E; }
  int pos = row_ptr[dst] + atomicAdd(&fill[dst], 1);
  col[pos] = src;
}

// ---------------- alpha dot-products: one wave per node, C=64 lanes ----------------
template <int NH>
__global__ __launch_bounds__(256) void alpha_kernel(const float* __restrict__ h,
                                                    const float* __restrict__ a_src,
                                                    const float* __restrict__ a_dst,
                                                    float* __restrict__ as_out,
                                                    float* __restrict__ ad_out, int N) {
  int w = (blockIdx.x * blockDim.x + threadIdx.x) >> 6;
  int lane = threadIdx.x & 63;
  if (w >= N) return;
  float s[NH], d[NH];
#pragma unroll
  for (int hh = 0; hh < NH; ++hh) {
    float v = h[(size_t)w * (NH * 64) + hh * 64 + lane];
    s[hh] = v * a_src[hh * 64 + lane];
    d[hh] = v * a_dst[hh * 64 + lane];
  }
#pragma unroll
  for (int hh = 0; hh < NH; ++hh) {
    for (int off = 32; off > 0; off >>= 1) {
      s[hh] += __shfl_xor(s[hh], off, 64);
      d[hh] += __shfl_xor(d[hh], off, 64);
    }
  }
  if (lane == 0) {
#pragma unroll
    for (int hh = 0; hh < NH; ++hh) {
      as_out[w * NH + hh] = s[hh];
      ad_out[w * NH + hh] = d[hh];
    }
  }
}

// ---------------- per-dst softmax + aggregation: one wave per dst node -------------
template <int NH>
__global__ __launch_bounds__(64) void agg_kernel(const float* __restrict__ h,
                                                 const float* __restrict__ as,
                                                 const float* __restrict__ ad,
                                                 const int* __restrict__ row_ptr,
                                                 const int* __restrict__ col,
                                                 const float* __restrict__ bias,
                                                 float* __restrict__ out, int N,
                                                 int do_elu) {
  const int dst = blockIdx.x;
  const int lane = threadIdx.x;
  const int s0 = row_ptr[dst], s1 = row_ptr[dst + 1];
  float adl[NH];
#pragma unroll
  for (int hh = 0; hh < NH; ++hh) adl[hh] = ad[dst * NH + hh];

  // pass 1: per-head max (lanes stride over edges)
  float m[NH];
#pragma unroll
  for (int hh = 0; hh < NH; ++hh) m[hh] = -1e30f;
  for (int i = s0 + lane; i < s1; i += 64) {
    int s = col[i];
#pragma unroll
    for (int hh = 0; hh < NH; ++hh) {
      float sc = leaky(as[s * NH + hh] + adl[hh]);
      m[hh] = fmaxf(m[hh], sc);
    }
  }
#pragma unroll
  for (int hh = 0; hh < NH; ++hh)
    for (int off = 32; off > 0; off >>= 1)
      m[hh] = fmaxf(m[hh], __shfl_xor(m[hh], off, 64));

  // pass 2: sum of exp
  float den[NH];
#pragma unroll
  for (int hh = 0; hh < NH; ++hh) den[hh] = 0.f;
  for (int i = s0 + lane; i < s1; i += 64) {
    int s = col[i];
#pragma unroll
    for (int hh = 0; hh < NH; ++hh) {
      float sc = leaky(as[s * NH + hh] + adl[hh]);
      den[hh] += __expf(sc - m[hh]);
    }
  }
#pragma unroll
  for (int hh = 0; hh < NH; ++hh) {
    for (int off = 32; off > 0; off >>= 1) den[hh] += __shfl_xor(den[hh], off, 64);
    den[hh] = 1.f / den[hh];
  }

  // pass 3: weighted feature aggregation — lane = channel, serial over edges
  float acc[NH];
#pragma unroll
  for (int hh = 0; hh < NH; ++hh) acc[hh] = 0.f;
  for (int i = s0; i < s1; ++i) {
    int s = col[i];
#pragma unroll
    for (int hh = 0; hh < NH; ++hh) {
      float sc = leaky(as[s * NH + hh] + adl[hh]);
      float wgt = __expf(sc - m[hh]) * den[hh];
      acc[hh] = fmaf(wgt, h[(size_t)s * (NH * 64) + hh * 64 + lane], acc[hh]);
    }
  }
#pragma unroll
  for (int hh = 0; hh < NH; ++hh) {
    float v = acc[hh] + bias[hh * 64 + lane];
    if (do_elu) v = v > 0.f ? v : (__expf(v) - 1.f);
    out[(size_t)dst * (NH * 64) + hh * 64 + lane] = v;
  }
}

extern "C" void kernel_launch(void* const* d_in, const int* in_sizes, int n_in,
                              void* d_out, int out_size, void* d_ws, size_t ws_size,
                              hipStream_t stream) {
  const float* x      = (const float*)d_in[0];
  const int*   ei     = (const int*)d_in[1];
  const float* W1     = (const float*)d_in[2];
  const float* a_src1 = (const float*)d_in[3];
  const float* a_dst1 = (const float*)d_in[4];
  const float* b1     = (const float*)d_in[5];
  const float* W2     = (const float*)d_in[6];
  const float* a_src2 = (const float*)d_in[7];
  const float* a_dst2 = (const float*)d_in[8];
  const float* b2     = (const float*)d_in[9];
  float* out = (float*)d_out;

  const int N = in_sizes[0] / IN_C;
  const int E = in_sizes[1] / 2;
  const int ET = E + N;

  char* ws = (char*)d_ws;
  size_t off = 0;
  auto alloc = [&](size_t bytes) -> void* {
    void* p = ws + off;
    off = (off + bytes + 255) & ~(size_t)255;
    return p;
  };
  float* h1      = (float*)alloc((size_t)N * F1 * 4);
  float* y1      = (float*)alloc((size_t)N * F1 * 4);
  float* h2      = (float*)alloc((size_t)N * OUT_C * 4);
  float* as1     = (float*)alloc((size_t)N * HEADS * 4);
  float* ad1     = (float*)alloc((size_t)N * HEADS * 4);
  float* as2     = (float*)alloc((size_t)N * 4);
  float* ad2     = (float*)alloc((size_t)N * 4);
  int*   deg     = (int*)alloc((size_t)N * 4);
  int*   row_ptr = (int*)alloc((size_t)(N + 1) * 4);
  int*   fill    = (int*)alloc((size_t)N * 4);
  int*   col     = (int*)alloc((size_t)ET * 4);
  (void)off; (void)ws_size; (void)n_in; (void)out_size;

  hipMemsetAsync(deg, 0, (size_t)N * 4, stream);
  hipMemsetAsync(fill, 0, (size_t)N * 4, stream);

  // CSR by destination (shared by both layers)
  degree_kernel<<<(ET + 255) / 256, 256, 0, stream>>>(ei, E, N, deg);
  scan_kernel<<<1, 1024, 0, stream>>>(deg, row_ptr, N);
  scatter_kernel<<<(ET + 255) / 256, 256, 0, stream>>>(ei, E, N, row_ptr, fill, col);

  // ---- layer 1 ----
  dim3 g1((N + 63) / 64, F1 / 64);
  gemm_nt<<<g1, 256, 0, stream>>>(x, W1, h1, N, F1, IN_C);
  alpha_kernel<HEADS><<<((size_t)N * 64 + 255) / 256, 256, 0, stream>>>(h1, a_src1, a_dst1, as1, ad1, N);
  agg_kernel<HEADS><<<N, 64, 0, stream>>>(h1, as1, ad1, row_ptr, col, b1, y1, N, 1);

  // ---- layer 2 ----
  dim3 g2((N + 63) / 64, OUT_C / 64);
  gemm_nt<<<g2, 256, 0, stream>>>(y1, W2, h2, N, OUT_C, F1);
  alpha_kernel<1><<<((size_t)N * 64 + 255) / 256, 256, 0, stream>>>(h2, a_src2, a_dst2, as2, ad2, N);
  agg_kernel<1><<<N, 64, 0, stream>>>(h2, as2, ad2, row_ptr, col, b2, out, N, 0);
}

// Round 2
// 735.937 us; speedup vs baseline: 1.3913x; 1.3913x over previous
//
#include <hip/hip_runtime.h>
#include <hip/hip_bf16.h>
#include <math.h>

constexpr int IN_C = 1024;
constexpr int HID = 64;
constexpr int HEADS = 4;
constexpr int F1 = HEADS * HID;  // 256
constexpr int OUT_C = 64;
constexpr float NEG = 0.2f;

using bf16x8 = __attribute__((ext_vector_type(8))) short;
using f32x4 = __attribute__((ext_vector_type(4))) float;

__device__ __forceinline__ float leaky(float x) { return x > 0.f ? x : NEG * x; }

__device__ __forceinline__ unsigned short bf16bits(float v) {
  __hip_bfloat16 b = __float2bfloat16(v);
  return *reinterpret_cast<unsigned short*>(&b);
}

// ---------------- f32 -> bf16 convert (for W1) ----------------
__global__ void cvt_bf16_kernel(const float* __restrict__ in,
                                unsigned short* __restrict__ out, int n) {
  int i = blockIdx.x * blockDim.x + threadIdx.x;
  if (i < n) out[i] = bf16bits(in[i]);
}

// ---------------- GEMM1: H[M,256] = X[M,1024] * W1[256,1024]^T via bf16 MFMA -------
// Block tile: 64(M) x 256(N=full). 4 waves, wave w covers n = w*64..w*64+63.
constexpr int BK = 64;
constexpr int LDT = BK + 8;  // ushort stride (144 B): 2-way-only LDS conflicts

__global__ __launch_bounds__(256, 3) void gemm1_mfma(const float* __restrict__ X,
                                                     const unsigned short* __restrict__ Wb,
                                                     float* __restrict__ H, int M) {
  __shared__ unsigned short As[64 * LDT];
  __shared__ unsigned short Bs[256 * LDT];
  const int tid = threadIdx.x;
  const int wave = tid >> 6;
  const int lane = tid & 63;
  const int m15 = lane & 15;
  const int q = lane >> 4;
  const int bm = blockIdx.x * 64;

  f32x4 acc[4][4];
#pragma unroll
  for (int i = 0; i < 4; ++i)
#pragma unroll
    for (int j = 0; j < 4; ++j) acc[i][j] = (f32x4){0.f, 0.f, 0.f, 0.f};

  const int ra = tid >> 4;          // 0..15 (A staging row within sub-pass)
  const int ca = (tid & 15) * 4;    // A f32 col
  const int rb = tid >> 3;          // 0..31 (B staging row within sub-pass)
  const int cb = (tid & 7) * 8;     // B bf16 col

  for (int kt = 0; kt < IN_C; kt += BK) {
    // stage A (f32 -> bf16), 4 sub-passes of 16 rows
#pragma unroll
    for (int j = 0; j < 4; ++j) {
      int row = j * 16 + ra;
      int gr = bm + row;
      float4 v = make_float4(0.f, 0.f, 0.f, 0.f);
      if (gr < M) v = *(const float4*)(X + (size_t)gr * IN_C + kt + ca);
      uint2 pk;
      pk.x = (unsigned)bf16bits(v.x) | ((unsigned)bf16bits(v.y) << 16);
      pk.y = (unsigned)bf16bits(v.z) | ((unsigned)bf16bits(v.w) << 16);
      *(uint2*)&As[row * LDT + ca] = pk;
    }
    // stage B (already bf16), 8 sub-passes of 32 rows
#pragma unroll
    for (int j = 0; j < 8; ++j) {
      int row = j * 32 + rb;
      uint4 v = *(const uint4*)(Wb + (size_t)row * IN_C + kt + cb);
      *(uint4*)&Bs[row * LDT + cb] = v;
    }
    __syncthreads();
#pragma unroll
    for (int k0 = 0; k0 < BK; k0 += 32) {
      bf16x8 af[4], bfr[4];
#pragma unroll
      for (int i = 0; i < 4; ++i)
        af[i] = *(const bf16x8*)&As[(i * 16 + m15) * LDT + k0 + q * 8];
#pragma unroll
      for (int j = 0; j < 4; ++j)
        bfr[j] = *(const bf16x8*)&Bs[(wave * 64 + j * 16 + m15) * LDT + k0 + q * 8];
#pragma unroll
      for (int i = 0; i < 4; ++i)
#pragma unroll
        for (int j = 0; j < 4; ++j)
          acc[i][j] = __builtin_amdgcn_mfma_f32_16x16x32_bf16(af[i], bfr[j], acc[i][j], 0, 0, 0);
    }
    __syncthreads();
  }
  // epilogue: D row = (lane>>4)*4 + reg (+ i*16), col = lane&15 (+ j*16 + wave*64)
#pragma unroll
  for (int i = 0; i < 4; ++i) {
#pragma unroll
    for (int r = 0; r < 4; ++r) {
      int row = bm + i * 16 + q * 4 + r;
      if (row < M) {
#pragma unroll
        for (int j = 0; j < 4; ++j)
          H[(size_t)row * F1 + wave * 64 + j * 16 + m15] = acc[i][j][r];
      }
    }
  }
}

// ---------------- GEMM (f32 VALU): C[M,N] = A[M,K] * B[N,K]^T  (layer 2) -----------
__global__ __launch_bounds__(256) void gemm_nt(const float* __restrict__ A,
                                               const float* __restrict__ B,
                                               float* __restrict__ C,
                                               int M, int N, int K) {
  __shared__ float As[32][68];
  __shared__ float Bs[32][68];
  const int bm = blockIdx.x * 64;
  const int bn = blockIdx.y * 64;
  const int tid = threadIdx.x;
  const int tx = tid & 15;
  const int ty = tid >> 4;
  float acc[4][4] = {{0.f, 0.f, 0.f, 0.f}};
  const int lr = tid >> 3;
  const int lc = (tid & 7) << 2;
  for (int kt = 0; kt < K; kt += 32) {
#pragma unroll
    for (int p = 0; p < 2; ++p) {
      int r = lr + p * 32;
      int gr = bm + r;
      float4 va = make_float4(0.f, 0.f, 0.f, 0.f);
      if (gr < M) va = *(const float4*)(A + (size_t)gr * K + kt + lc);
      As[lc + 0][r] = va.x; As[lc + 1][r] = va.y;
      As[lc + 2][r] = va.z; As[lc + 3][r] = va.w;
      int gn = bn + r;
      float4 vb = make_float4(0.f, 0.f, 0.f, 0.f);
      if (gn < N) vb = *(const float4*)(B + (size_t)gn * K + kt + lc);
      Bs[lc + 0][r] = vb.x; Bs[lc + 1][r] = vb.y;
      Bs[lc + 2][r] = vb.z; Bs[lc + 3][r] = vb.w;
    }
    __syncthreads();
#pragma unroll
    for (int k = 0; k < 32; ++k) {
      float4 a = *(const float4*)&As[k][ty * 4];
      float4 b = *(const float4*)&Bs[k][tx * 4];
      float av[4] = {a.x, a.y, a.z, a.w};
      float bv[4] = {b.x, b.y, b.z, b.w};
#pragma unroll
      for (int i = 0; i < 4; ++i)
#pragma unroll
        for (int j = 0; j < 4; ++j) acc[i][j] = fmaf(av[i], bv[j], acc[i][j]);
    }
    __syncthreads();
  }
#pragma unroll
  for (int i = 0; i < 4; ++i) {
    int row = bm + ty * 4 + i;
    if (row < M) {
#pragma unroll
      for (int j = 0; j < 4; ++j)
        C[(size_t)row * N + bn + tx * 4 + j] = acc[i][j];
    }
  }
}

// ---------------- CSR build ----------------
__global__ void degree_kernel(const int* __restrict__ ei, int E, int N,
                              int* __restrict__ deg) {
  int e = blockIdx.x * blockDim.x + threadIdx.x;
  if (e >= E + N) return;
  int dst = (e < E) ? ei[E + e] : (e - E);
  atomicAdd(&deg[dst], 1);
}

__global__ __launch_bounds__(256) void scan_block_sums(const int* __restrict__ deg,
                                                       int* __restrict__ part, int n) {
  __shared__ int sm[256];
  int t = threadIdx.x;
  int i = blockIdx.x * 256 + t;
  sm[t] = (i < n) ? deg[i] : 0;
  __syncthreads();
  for (int off = 128; off > 0; off >>= 1) {
    if (t < off) sm[t] += sm[t + off];
    __syncthreads();
  }
  if (t == 0) part[blockIdx.x] = sm[0];
}

__global__ __launch_bounds__(256) void scan_partials(int* __restrict__ part, int P) {
  __shared__ int sm[256];
  int t = threadIdx.x;
  int v = (t < P) ? part[t] : 0;
  sm[t] = v;
  __syncthreads();
  for (int off = 1; off < 256; off <<= 1) {
    int u = (t >= off) ? sm[t - off] : 0;
    __syncthreads();
    sm[t] += u;
    __syncthreads();
  }
  if (t < P) part[t] = sm[t];  // inclusive
}

__global__ __launch_bounds__(256) void scan_final(const int* __restrict__ deg,
                                                  const int* __restrict__ part,
                                                  int* __restrict__ row_ptr, int n) {
  __shared__ int sm[256];
  int t = threadIdx.x;
  int i = blockIdx.x * 256 + t;
  sm[t] = (i < n) ? deg[i] : 0;
  __syncthreads();
  for (int off = 1; off < 256; off <<= 1) {
    int u = (t >= off) ? sm[t - off] : 0;
    __syncthreads();
    sm[t] += u;
    __syncthreads();
  }
  int base = blockIdx.x ? part[blockIdx.x - 1] : 0;
  if (i < n) row_ptr[i + 1] = base + sm[t];
  if (i == 0) row_ptr[0] = 0;
}

__global__ void scatter_kernel(const int* __restrict__ ei, int E, int N,
                               const int* __restrict__ row_ptr, int* __restrict__ fill,
                               int* __restrict__ col) {
  int e = blockIdx.x * blockDim.x + threadIdx.x;
  if (e >= E + N) return;
  int src, dst;
  if (e < E) { src = ei[e]; dst = ei[E + e]; }
  else       { src = e - E; dst = e - E; }
  int pos = row_ptr[dst] + atomicAdd(&fill[dst], 1);
  col[pos] = src;
}

// ---------------- alpha dot-products: one wave per node ----------------
template <int NH>
__global__ __launch_bounds__(256) void alpha_kernel(const float* __restrict__ h,
                                                    const float* __restrict__ a_src,
                                                    const float* __restrict__ a_dst,
                                                    float* __restrict__ as_out,
                                                    float* __restrict__ ad_out, int N) {
  int w = (blockIdx.x * blockDim.x + threadIdx.x) >> 6;
  int lane = threadIdx.x & 63;
  if (w >= N) return;
  float s[NH], d[NH];
#pragma unroll
  for (int hh = 0; hh < NH; ++hh) {
    float v = h[(size_t)w * (NH * 64) + hh * 64 + lane];
    s[hh] = v * a_src[hh * 64 + lane];
    d[hh] = v * a_dst[hh * 64 + lane];
  }
#pragma unroll
  for (int hh = 0; hh < NH; ++hh) {
    for (int off = 32; off > 0; off >>= 1) {
      s[hh] += __shfl_xor(s[hh], off, 64);
      d[hh] += __shfl_xor(d[hh], off, 64);
    }
  }
  if (lane == 0) {
#pragma unroll
    for (int hh = 0; hh < NH; ++hh) {
      as_out[w * NH + hh] = s[hh];
      ad_out[w * NH + hh] = d[hh];
    }
  }
}

// ------- per-dst softmax + aggregation: 4 waves/block, one dst per wave -----------
template <int NH>
__global__ __launch_bounds__(256) void agg_kernel(const float* __restrict__ h,
                                                  const float* __restrict__ as,
                                                  const float* __restrict__ ad,
                                                  const int* __restrict__ row_ptr,
                                                  const int* __restrict__ col,
                                                  const float* __restrict__ bias,
                                                  float* __restrict__ out, int N,
                                                  int do_elu) {
  constexpr int CAP = 96;
  __shared__ float exs[4][CAP * NH];
  const int wv = threadIdx.x >> 6;
  const int lane = threadIdx.x & 63;
  const int dst = blockIdx.x * 4 + wv;
  if (dst >= N) return;
  const int s0 = row_ptr[dst], s1 = row_ptr[dst + 1];
  float adl[NH];
#pragma unroll
  for (int hh = 0; hh < NH; ++hh) adl[hh] = ad[dst * NH + hh];

  // pass 1: per-head max (lanes stride edges)
  float m[NH];
#pragma unroll
  for (int hh = 0; hh < NH; ++hh) m[hh] = -1e30f;
  for (int i = s0 + lane; i < s1; i += 64) {
    int s = col[i];
    if (NH == 4) {
      float4 a4 = *(const float4*)(as + (size_t)s * 4);
      float av[4] = {a4.x, a4.y, a4.z, a4.w};
#pragma unroll
      for (int hh = 0; hh < 4; ++hh) m[hh] = fmaxf(m[hh], leaky(av[hh] + adl[hh]));
    } else {
      m[0] = fmaxf(m[0], leaky(as[s] + adl[0]));
    }
  }
#pragma unroll
  for (int hh = 0; hh < NH; ++hh)
    for (int off = 32; off > 0; off >>= 1)
      m[hh] = fmaxf(m[hh], __shfl_xor(m[hh], off, 64));

  // pass 2: sum of exp; cache exp values in LDS
  float den[NH];
#pragma unroll
  for (int hh = 0; hh < NH; ++hh) den[hh] = 0.f;
  for (int i = s0 + lane; i < s1; i += 64) {
    int s = col[i];
    int idx = i - s0;
    if (NH == 4) {
      float4 a4 = *(const float4*)(as + (size_t)s * 4);
      float av[4] = {a4.x, a4.y, a4.z, a4.w};
#pragma unroll
      for (int hh = 0; hh < 4; ++hh) {
        float e = __expf(leaky(av[hh] + adl[hh]) - m[hh]);
        den[hh] += e;
        if (idx < CAP) exs[wv][idx * NH + hh] = e;
      }
    } else {
      float e = __expf(leaky(as[s] + adl[0]) - m[0]);
      den[0] += e;
      if (idx < CAP) exs[wv][idx] = e;
    }
  }
  float inv[NH];
#pragma unroll
  for (int hh = 0; hh < NH; ++hh) {
    for (int off = 32; off > 0; off >>= 1) den[hh] += __shfl_xor(den[hh], off, 64);
    inv[hh] = 1.f / den[hh];
  }
  __asm__ __volatile__("s_waitcnt lgkmcnt(0)");  // same-wave LDS RAW drain

  // pass 3: weighted aggregation — lane = channel, serial over edges
  float acc[NH];
#pragma unroll
  for (int hh = 0; hh < NH; ++hh) acc[hh] = 0.f;
  for (int i = s0; i < s1; ++i) {
    int s = col[i];
    int idx = i - s0;
    float e[NH];
    if (idx < CAP) {
#pragma unroll
      for (int hh = 0; hh < NH; ++hh) e[hh] = exs[wv][idx * NH + hh];
    } else {
      if (NH == 4) {
        float4 a4 = *(const float4*)(as + (size_t)s * 4);
        float av[4] = {a4.x, a4.y, a4.z, a4.w};
#pragma unroll
        for (int hh = 0; hh < 4; ++hh) e[hh] = __expf(leaky(av[hh] + adl[hh]) - m[hh]);
      } else {
        e[0] = __expf(leaky(as[s] + adl[0]) - m[0]);
      }
    }
#pragma unroll
    for (int hh = 0; hh < NH; ++hh)
      acc[hh] = fmaf(e[hh], h[(size_t)s * (NH * 64) + hh * 64 + lane], acc[hh]);
  }
#pragma unroll
  for (int hh = 0; hh < NH; ++hh) {
    float v = acc[hh] * inv[hh] + bias[hh * 64 + lane];
    if (do_elu) v = v > 0.f ? v : (__expf(v) - 1.f);
    out[(size_t)dst * (NH * 64) + hh * 64 + lane] = v;
  }
}

extern "C" void kernel_launch(void* const* d_in, const int* in_sizes, int n_in,
                              void* d_out, int out_size, void* d_ws, size_t ws_size,
                              hipStream_t stream) {
  const float* x      = (const float*)d_in[0];
  const int*   ei     = (const int*)d_in[1];
  const float* W1     = (const float*)d_in[2];
  const float* a_src1 = (const float*)d_in[3];
  const float* a_dst1 = (const float*)d_in[4];
  const float* b1     = (const float*)d_in[5];
  const float* W2     = (const float*)d_in[6];
  const float* a_src2 = (const float*)d_in[7];
  const float* a_dst2 = (const float*)d_in[8];
  const float* b2     = (const float*)d_in[9];
  float* out = (float*)d_out;

  const int N = in_sizes[0] / IN_C;
  const int E = in_sizes[1] / 2;
  const int ET = E + N;

  char* ws = (char*)d_ws;
  size_t off = 0;
  auto alloc = [&](size_t bytes) -> void* {
    void* p = ws + off;
    off = (off + bytes + 255) & ~(size_t)255;
    return p;
  };
  float* h1      = (float*)alloc((size_t)N * F1 * 4);
  float* y1      = (float*)alloc((size_t)N * F1 * 4);
  float* h2      = (float*)alloc((size_t)N * OUT_C * 4);
  float* as1     = (float*)alloc((size_t)N * HEADS * 4);
  float* ad1     = (float*)alloc((size_t)N * HEADS * 4);
  float* as2     = (float*)alloc((size_t)N * 4);
  float* ad2     = (float*)alloc((size_t)N * 4);
  int*   deg     = (int*)alloc((size_t)N * 4);
  int*   row_ptr = (int*)alloc((size_t)(N + 1) * 4);
  int*   fill    = (int*)alloc((size_t)N * 4);
  int*   col     = (int*)alloc((size_t)ET * 4);
  int*   part    = (int*)alloc(1024 * 4);
  unsigned short* W1b = (unsigned short*)alloc((size_t)F1 * IN_C * 2);
  (void)off; (void)ws_size; (void)n_in; (void)out_size;

  hipMemsetAsync(deg, 0, (size_t)N * 4, stream);
  hipMemsetAsync(fill, 0, (size_t)N * 4, stream);

  // W1 -> bf16
  cvt_bf16_kernel<<<(F1 * IN_C + 255) / 256, 256, 0, stream>>>(W1, W1b, F1 * IN_C);

  // CSR by destination (shared by both layers)
  const int P = (N + 255) / 256;
  degree_kernel<<<(ET + 255) / 256, 256, 0, stream>>>(ei, E, N, deg);
  scan_block_sums<<<P, 256, 0, stream>>>(deg, part, N);
  scan_partials<<<1, 256, 0, stream>>>(part, P);
  scan_final<<<P, 256, 0, stream>>>(deg, part, row_ptr, N);
  scatter_kernel<<<(ET + 255) / 256, 256, 0, stream>>>(ei, E, N, row_ptr, fill, col);

  // ---- layer 1 ----
  gemm1_mfma<<<(N + 63) / 64, 256, 0, stream>>>(x, W1b, h1, N);
  alpha_kernel<HEADS><<<((size_t)N * 64 + 255) / 256, 256, 0, stream>>>(h1, a_src1, a_dst1, as1, ad1, N);
  agg_kernel<HEADS><<<(N + 3) / 4, 256, 0, stream>>>(h1, as1, ad1, row_ptr, col, b1, y1, N, 1);

  // ---- layer 2 ----
  dim3 g2((N + 63) / 64, OUT_C / 64);
  gemm_nt<<<g2, 256, 0, stream>>>(y1, W2, h2, N, OUT_C, F1);
  alpha_kernel<1><<<((size_t)N * 64 + 255) / 256, 256, 0, stream>>>(h2, a_src2, a_dst2, as2, ad2, N);
  agg_kernel<1><<<(N + 3) / 4, 256, 0, stream>>>(h2, as2, ad2, row_ptr, col, b2, out, N, 0);
}